// Round 1
// baseline (1761.496 us; speedup 1.0000x reference)
//
#include <hip/hip_runtime.h>
#include <math.h>

#define NEG_SLOPE 0.2f

// ---------- helpers ----------
__device__ __forceinline__ unsigned enc_f(float f) {
    unsigned b = __float_as_uint(f);
    return (b & 0x80000000u) ? ~b : (b | 0x80000000u);
}
__device__ __forceinline__ float dec_f(unsigned k) {
    unsigned b = (k & 0x80000000u) ? (k & 0x7FFFFFFFu) : ~k;
    return __uint_as_float(b);
}
__device__ __forceinline__ void atomAddF(float* p, float v) {
    unsafeAtomicAdd(p, v);   // HW global_atomic_add_f32 on gfx950
}

// ---------- RGAT kernels ----------
// Vsrc[r*64+d] = sum_e W[r,d,e]*a_src[r,e];  Vdst analogous.
__global__ void compute_v_kernel(const float* __restrict__ W,
                                 const float* __restrict__ a_src,
                                 const float* __restrict__ a_dst,
                                 float* __restrict__ Vsrc, float* __restrict__ Vdst,
                                 int R) {
    int idx = blockIdx.x * blockDim.x + threadIdx.x;   // r*64+d
    if (idx >= R * 64) return;
    int r = idx >> 6;
    const float* Wr = W + idx * 64;            // row (r,d,:)
    const float* as = a_src + r * 64;
    const float* ad = a_dst + r * 64;
    float s = 0.f, t = 0.f;
    for (int e = 0; e < 64; e++) { float w = Wr[e]; s = fmaf(w, as[e], s); t = fmaf(w, ad[e], t); }
    Vsrc[idx] = s; Vdst[idx] = t;
}

// attS[n*R+r] = h[n,:] . Vsrc[r,:]   (one wave per node)
__global__ void node_att_kernel(const float* __restrict__ h,
                                const float* __restrict__ Vsrc,
                                const float* __restrict__ Vdst,
                                float* __restrict__ attS, float* __restrict__ attD,
                                int N, int R) {
    int wave = (blockIdx.x * blockDim.x + threadIdx.x) >> 6;
    int lane = threadIdx.x & 63;
    if (wave >= N) return;
    float x = h[wave * 64 + lane];
    for (int r = 0; r < R; r++) {
        float s = x * Vsrc[r * 64 + lane];
        float t = x * Vdst[r * 64 + lane];
        for (int o = 32; o; o >>= 1) { s += __shfl_xor(s, o); t += __shfl_xor(t, o); }
        if (lane == 0) { attS[wave * R + r] = s; attD[wave * R + r] = t; }
    }
}

__global__ void init_seg_kernel(unsigned* __restrict__ segmax, float* __restrict__ segsum, int N) {
    int i = blockIdx.x * blockDim.x + threadIdx.x;
    if (i < N) { segmax[i] = enc_f(-INFINITY); segsum[i] = 0.f; }
}

__global__ void edge_score_kernel(const int* __restrict__ src, const int* __restrict__ dst,
                                  const int* __restrict__ rel,
                                  const float* __restrict__ attS, const float* __restrict__ attD,
                                  float* __restrict__ scores, unsigned* __restrict__ segmax,
                                  int E, int R) {
    int e = blockIdx.x * blockDim.x + threadIdx.x;
    if (e >= E) return;
    int r = rel[e];
    float sc = attS[src[e] * R + r] + attD[dst[e] * R + r];
    sc = sc > 0.f ? sc : NEG_SLOPE * sc;
    scores[e] = sc;
    atomicMax(&segmax[dst[e]], enc_f(sc));
}

// in-place: scores[e] <- exp(scores[e]-max); accumulate segsum
__global__ void edge_exp_kernel(const int* __restrict__ dst, float* __restrict__ scores,
                                const unsigned* __restrict__ segmax, float* __restrict__ segsum,
                                int E) {
    int e = blockIdx.x * blockDim.x + threadIdx.x;
    if (e >= E) return;
    int d = dst[e];
    float ex = expf(scores[e] - dec_f(segmax[d]));
    scores[e] = ex;
    atomAddF(&segsum[d], ex);
}

// one wave per edge: agg[dst] += alpha * (h[src] @ W[rel])
__global__ void edge_msg_kernel(const int* __restrict__ src, const int* __restrict__ dst,
                                const int* __restrict__ rel, const float* __restrict__ ex,
                                const float* __restrict__ segsum, const float* __restrict__ h,
                                const float* __restrict__ W, float* __restrict__ agg, int E) {
    int wv = (blockIdx.x * blockDim.x + threadIdx.x) >> 6;
    int lane = threadIdx.x & 63;
    if (wv >= E) return;
    int s = src[wv], d = dst[wv], r = rel[wv];
    float alpha = ex[wv] / (segsum[d] + 1e-9f);
    float x = h[s * 64 + lane] * alpha;
    const float* Wr = W + r * 4096 + lane;
    float acc = 0.f;
#pragma unroll
    for (int k = 0; k < 64; k++) {
        float hv = __shfl(x, k);
        acc = fmaf(hv, Wr[k * 64], acc);
    }
    atomAddF(&agg[d * 64 + lane], acc);
}

__global__ void elu_kernel(float* __restrict__ x, int n) {
    int i = blockIdx.x * blockDim.x + threadIdx.x;
    if (i < n) { float v = x[i]; x[i] = v > 0.f ? v : expm1f(v); }
}

// out[seg[n]*64+d] += h[n*64+d]
__global__ void seg_sum64_kernel(const float* __restrict__ h, const int* __restrict__ seg,
                                 float* __restrict__ out, int N) {
    int i = blockIdx.x * blockDim.x + threadIdx.x;
    if (i >= N * 64) return;
    int n = i >> 6, d = i & 63;
    atomAddF(&out[seg[n] * 64 + d], h[i]);
}

// feat[b,0:64] += molr[m]; feat[b,64:128] += mol[m]
__global__ void readout_kernel(const float* __restrict__ molr, const float* __restrict__ mol,
                               const int* __restrict__ mol2rxn, float* __restrict__ feat, int M) {
    int i = blockIdx.x * blockDim.x + threadIdx.x;
    if (i >= M * 64) return;
    int m = i >> 6, d = i & 63;
    int b = mol2rxn[m];
    atomAddF(&feat[b * 128 + d], molr[i]);
    atomAddF(&feat[b * 128 + 64 + d], mol[i]);
}

// hm[b,j] = PReLU(feat[b,:] @ w_fc1[:,j] + b_fc1[j])  (block=512, grid=1024)
__global__ void fc1_kernel(const float* __restrict__ feat, const float* __restrict__ w,
                           const float* __restrict__ bias, const float* __restrict__ prelu,
                           float* __restrict__ hm) {
    __shared__ float f[128];
    int b = blockIdx.x, j = threadIdx.x;
    if (j < 128) f[j] = feat[b * 128 + j];
    __syncthreads();
    float acc = bias[j];
#pragma unroll 8
    for (int k = 0; k < 128; k++) acc = fmaf(f[k], w[k * 512 + j], acc);
    float p = *prelu;
    hm[b * 512 + j] = acc > 0.f ? acc : p * acc;
}

// out[b,o] = hm[b,:] @ w_fc2[:,o] + b_fc2[o]
__global__ void fc2_kernel(const float* __restrict__ hm, const float* __restrict__ w,
                           const float* __restrict__ bias, float* __restrict__ out) {
    __shared__ float f[512];
    int b = blockIdx.y;
    int j = blockIdx.x * blockDim.x + threadIdx.x;
    for (int k = threadIdx.x; k < 512; k += blockDim.x) f[k] = hm[b * 512 + k];
    __syncthreads();
    if (j >= 703) return;
    float acc = bias[j];
    for (int k = 0; k < 512; k++) acc = fmaf(f[k], w[k * 703 + j], acc);
    out[b * 703 + j] = acc;
}

// ---------- launch ----------
extern "C" void kernel_launch(void* const* d_in, const int* in_sizes, int n_in,
                              void* d_out, int out_size, void* d_ws, size_t ws_size,
                              hipStream_t stream) {
    const float* node_feats = (const float*)d_in[0];
    const int*   edge_src   = (const int*)d_in[1];
    const int*   edge_dst   = (const int*)d_in[2];
    const int*   edge_rel   = (const int*)d_in[3];
    const int*   node2mol   = (const int*)d_in[4];
    const int*   rxn_src    = (const int*)d_in[5];
    const int*   rxn_dst    = (const int*)d_in[6];
    const int*   rxn_rel    = (const int*)d_in[7];
    const int*   mol2rxn    = (const int*)d_in[8];
    const float* W1     = (const float*)d_in[9];
    const float* a_src1 = (const float*)d_in[10];
    const float* a_dst1 = (const float*)d_in[11];
    const float* W2     = (const float*)d_in[12];
    const float* a_src2 = (const float*)d_in[13];
    const float* a_dst2 = (const float*)d_in[14];
    const float* Wr     = (const float*)d_in[15];
    const float* a_srcr = (const float*)d_in[16];
    const float* a_dstr = (const float*)d_in[17];
    const float* w_fc1  = (const float*)d_in[18];
    const float* b_fc1  = (const float*)d_in[19];
    const float* prelu1 = (const float*)d_in[20];
    const float* w_fc2  = (const float*)d_in[21];
    const float* b_fc2  = (const float*)d_in[22];

    const int N = 100000, E = 800000, M = 5000, ER = 40000;

    float* ws = (float*)d_ws;
    float* h1     = ws;                    // 6,400,000
    float* h2     = h1 + 6400000;          // 6,400,000
    float* attS   = h2 + 6400000;          // 800,000
    float* attD   = attS + 800000;         // 800,000
    float* scores = attD + 800000;         // 800,000
    unsigned* segmax = (unsigned*)(scores + 800000);  // 100,000
    float* segsum = (float*)(segmax + 100000);        // 100,000
    float* mol    = segsum + 100000;       // 320,000
    float* molr   = mol + 320000;          // 320,000
    float* feat   = molr + 320000;         // 131,072
    float* hm     = feat + 131072;         // 524,288
    float* Vsrc   = hm + 524288;           // 512
    float* Vdst   = Vsrc + 512;            // 512

    auto rgat = [&](const float* hin, int n, int e, const int* es, const int* ed,
                    const int* er, const float* W, const float* as, const float* ad,
                    float* agg, int R) {
        compute_v_kernel<<<dim3((R * 64 + 63) / 64), 64, 0, stream>>>(W, as, ad, Vsrc, Vdst, R);
        node_att_kernel<<<dim3((n * 64 + 255) / 256), 256, 0, stream>>>(hin, Vsrc, Vdst, attS, attD, n, R);
        init_seg_kernel<<<dim3((n + 255) / 256), 256, 0, stream>>>(segmax, segsum, n);
        edge_score_kernel<<<dim3((e + 255) / 256), 256, 0, stream>>>(es, ed, er, attS, attD, scores, segmax, e, R);
        edge_exp_kernel<<<dim3((e + 255) / 256), 256, 0, stream>>>(ed, scores, segmax, segsum, e);
        hipMemsetAsync(agg, 0, (size_t)n * 64 * sizeof(float), stream);
        edge_msg_kernel<<<dim3((e * 64 + 255) / 256), 256, 0, stream>>>(es, ed, er, scores, segsum, hin, W, agg, e);
        elu_kernel<<<dim3((n * 64 + 255) / 256), 256, 0, stream>>>(agg, n * 64);
    };

    // atom-level RGAT x2
    rgat(node_feats, N, E, edge_src, edge_dst, edge_rel, W1, a_src1, a_dst1, h1, 8);
    rgat(h1,         N, E, edge_src, edge_dst, edge_rel, W2, a_src2, a_dst2, h2, 8);

    // molecule pooling
    hipMemsetAsync(mol, 0, (size_t)M * 64 * sizeof(float), stream);
    seg_sum64_kernel<<<dim3((N * 64 + 255) / 256), 256, 0, stream>>>(h2, node2mol, mol, N);

    // reaction-graph RGAT
    rgat(mol, M, ER, rxn_src, rxn_dst, rxn_rel, Wr, a_srcr, a_dstr, molr, 4);

    // reaction readout
    hipMemsetAsync(feat, 0, (size_t)1024 * 128 * sizeof(float), stream);
    readout_kernel<<<dim3((M * 64 + 255) / 256), 256, 0, stream>>>(molr, mol, mol2rxn, feat, M);

    // MLP head
    fc1_kernel<<<dim3(1024), 512, 0, stream>>>(feat, w_fc1, b_fc1, prelu1, hm);
    fc2_kernel<<<dim3(3, 1024), 256, 0, stream>>>(hm, w_fc2, b_fc2, (float*)d_out);
}